// Round 1
// baseline (3526.697 us; speedup 1.0000x reference)
//
#include <hip/hip_runtime.h>
#include <math.h>

#define BLOCK 512
#define ROWS 8

// ---- LDS layout (float offsets) ----
static constexpr int OFF_W1    = 0;        // 60*128 = 7680
static constexpr int OFF_W2    = 7680;     // 128*128 = 16384
static constexpr int OFF_W3    = 24064;    // 8*132 = 1056 (transposed, padded)
static constexpr int OFF_B1    = 25120;    // 128
static constexpr int OFF_B2    = 25248;    // 128
static constexpr int OFF_B3    = 25376;    // 8
static constexpr int OFF_STATE = 25384;    // 8 rows * 64
static constexpr int OFF_INP   = 25896;    // 8 rows * 64
static constexpr int OFF_H1    = 26408;    // 8 rows * 128
static constexpr int OFF_H2    = 27432;    // 8 rows * 128
static constexpr int OFF_NN    = 28456;    // 8 rows * 8
static constexpr int OFF_KACC  = 28520;    // 8 rows * 8
static constexpr int OFF_SU    = 28584;    // 8 rows * 256 (preloaded useq)
static constexpr int LDS_FLOATS = 30632;   // 122528 bytes

extern "C" __global__ void __launch_bounds__(BLOCK, 2)
cstr_rk4(const float* __restrict__ useq, const float* __restrict__ xGz0,
         const float* __restrict__ W1, const float* __restrict__ b1,
         const float* __restrict__ W2, const float* __restrict__ b2,
         const float* __restrict__ W3, const float* __restrict__ b3,
         float* __restrict__ out)
{
    extern __shared__ float sm[];
    float* sW1    = sm + OFF_W1;
    float* sW2    = sm + OFF_W2;
    float* sW3    = sm + OFF_W3;
    float* sb1    = sm + OFF_B1;
    float* sb2    = sm + OFF_B2;
    float* sb3    = sm + OFF_B3;
    float* sstate = sm + OFF_STATE;
    float* sinp   = sm + OFF_INP;
    float* sh1    = sm + OFF_H1;
    float* sh2    = sm + OFF_H2;
    float* snn    = sm + OFF_NN;
    float* skacc  = sm + OFF_KACC;
    float* su     = sm + OFF_SU;

    const int tid  = threadIdx.x;
    const int base = blockIdx.x * ROWS;

    // ---- stage weights / biases / inputs into LDS ----
    for (int i = tid; i < 7680; i += BLOCK)  sW1[i] = W1[i];
    for (int i = tid; i < 16384; i += BLOCK) sW2[i] = W2[i];
    for (int i = tid; i < 1024; i += BLOCK)  sW3[(i & 7) * 132 + (i >> 3)] = W3[i];
    if (tid < 128) { sb1[tid] = b1[tid]; sb2[tid] = b2[tid]; }
    if (tid < 8)   sb3[tid] = b3[tid];
    for (int i = tid; i < ROWS * 256; i += BLOCK) su[i] = useq[(size_t)base * 256 + i];
    for (int i = tid; i < ROWS * 64; i += BLOCK) {
        int r = i >> 6, c = i & 63;
        sstate[i] = (c < 58) ? xGz0[(size_t)(base + r) * 58 + c] : 0.f;
    }
    __syncthreads();

    const int g  = tid >> 7;      // group 0..3 (128 threads each)
    const int j  = tid & 127;     // hidden index
    const int r0 = g * 2, r1 = r0 + 1;

    for (int t = 0; t < 128; ++t) {
        // ---- P0: build inp = [xG, z, u]; emit y = xG ----
        {
            int r = -1, k = 0;
            if (j < 60)                { r = r0; k = j; }
            else if (j >= 64 && j < 124) { r = r1; k = j - 64; }
            if (r >= 0) {
                float v = (k < 58) ? sstate[r * 64 + k]
                                   : su[r * 256 + t * 2 + (k - 58)];
                sinp[r * 64 + k] = v;
                if (k < 8) out[((size_t)(base + r) * 128 + t) * 8 + k] = v;
            }
        }
        __syncthreads();

        for (int s = 0; s < 4; ++s) {
            // ---- L1: h1 = tanh(inp @ W1 + b1) ----
            {
                float a0 = sb1[j], a1 = a0;
                const float* i0 = sinp + r0 * 64;
                const float* i1 = sinp + r1 * 64;
                #pragma unroll
                for (int kk = 0; kk < 15; ++kk) {
                    float4 v0 = *(const float4*)(i0 + kk * 4);
                    float4 v1 = *(const float4*)(i1 + kk * 4);
                    const float* wp = sW1 + kk * 4 * 128 + j;
                    a0 = fmaf(v0.x, wp[0],   a0);  a1 = fmaf(v1.x, wp[0],   a1);
                    a0 = fmaf(v0.y, wp[128], a0);  a1 = fmaf(v1.y, wp[128], a1);
                    a0 = fmaf(v0.z, wp[256], a0);  a1 = fmaf(v1.z, wp[256], a1);
                    a0 = fmaf(v0.w, wp[384], a0);  a1 = fmaf(v1.w, wp[384], a1);
                }
                sh1[r0 * 128 + j] = tanhf(a0);
                sh1[r1 * 128 + j] = tanhf(a1);
            }
            __syncthreads();
            // ---- L2: h2 = tanh(h1 @ W2 + b2) ----
            {
                float a0 = sb2[j], a1 = a0;
                const float* i0 = sh1 + r0 * 128;
                const float* i1 = sh1 + r1 * 128;
                #pragma unroll
                for (int kk = 0; kk < 32; ++kk) {
                    float4 v0 = *(const float4*)(i0 + kk * 4);
                    float4 v1 = *(const float4*)(i1 + kk * 4);
                    const float* wp = sW2 + kk * 4 * 128 + j;
                    a0 = fmaf(v0.x, wp[0],   a0);  a1 = fmaf(v1.x, wp[0],   a1);
                    a0 = fmaf(v0.y, wp[128], a0);  a1 = fmaf(v1.y, wp[128], a1);
                    a0 = fmaf(v0.z, wp[256], a0);  a1 = fmaf(v1.z, wp[256], a1);
                    a0 = fmaf(v0.w, wp[384], a0);  a1 = fmaf(v1.w, wp[384], a1);
                }
                sh2[r0 * 128 + j] = tanhf(a0);
                sh2[r1 * 128 + j] = tanhf(a1);
            }
            __syncthreads();
            // ---- L3: nn = h2 @ W3 + b3 (8 lanes per row) ----
            {
                int r = -1;
                if (j < 8)                  r = r0;
                else if (j >= 64 && j < 72) r = r1;
                if (r >= 0) {
                    int o = j & 7;
                    float a = sb3[o];
                    const float* hp = sh2 + r * 128;
                    const float* wp = sW3 + o * 132;
                    #pragma unroll
                    for (int kk = 0; kk < 32; ++kk) {
                        float4 hv = *(const float4*)(hp + kk * 4);
                        float4 wv = *(const float4*)(wp + kk * 4);
                        a = fmaf(hv.x, wv.x, a);
                        a = fmaf(hv.y, wv.y, a);
                        a = fmaf(hv.z, wv.z, a);
                        a = fmaf(hv.w, wv.w, a);
                    }
                    snn[r * 8 + o] = a;
                }
            }
            __syncthreads();
            // ---- finish: k = fg + nn; RK bookkeeping; stage-dependent z build ----
            {
                int lr = (j == 0) ? r0 : ((j == 64) ? r1 : -1);
                if (lr >= 0) {
                    float x0 = sinp[lr*64+0], x1 = sinp[lr*64+1];
                    float x2v = sinp[lr*64+2], x3v = sinp[lr*64+3];
                    float x4v = sinp[lr*64+4], x5 = sinp[lr*64+5];
                    float x6 = sinp[lr*64+6], x7 = sinp[lr*64+7];
                    float u0 = sinp[lr*64+58], u1 = sinp[lr*64+59];
                    float Hr  = x0*2.f + 50.f,   CAr = x1*0.2f + 1.f;
                    float CBr = x2v*0.1f + 0.5f, Tr  = x3v*4.f + 313.f;
                    float Hb  = x4v*2.f + 50.f,  CAb = x5*0.2f + 1.f;
                    float CBb = x6*0.1f + 0.5f,  Tb  = x7*4.f + 313.f;
                    float F = u0 + 10.f, D = u1*0.5f + 5.f;
                    float Fr = 2.5f * sqrtf(Hr);
                    float Fb = 1.5f * sqrtf(Hb);
                    float rH = 1.f / (3.f * Hr), rB = 1.f / (3.f * Hb);
                    float d0 = (F + D - Fr) * (1.f/3.f);
                    float d1 = (F*(6.f - CAr) - D*CAr) * rH;
                    float d2 = (-F*CBr - D*CBr) * rH;
                    float d3 = (F*(320.f - Tr) + D*(300.f - Tr)) * rH + 200.f/(90.f*Hr);
                    float d4 = (Fr - Fb - D) * (1.f/3.f);
                    float d5 = (Fr*(CAr - CAb) + D*CAb) * rB;
                    float d6 = (Fr*(CBb - CBb) + 0.f) * rB; // placeholder overwritten below
                    d6 = (Fr*(CBr - CBb) + D*CBb) * rB;
                    float d7 = Fr*(Tr - Tb)*rB + 200.f/(90.f*Hb);
                    float kv[8];
                    kv[0] = d0*0.5f  + snn[lr*8+0];
                    kv[1] = d1*5.f   + snn[lr*8+1];
                    kv[2] = d2*10.f  + snn[lr*8+2];
                    kv[3] = d3*0.25f + snn[lr*8+3];
                    kv[4] = d4*0.5f  + snn[lr*8+4];
                    kv[5] = d5*5.f   + snn[lr*8+5];
                    kv[6] = d6*10.f  + snn[lr*8+6];
                    kv[7] = d7*0.25f + snn[lr*8+7];
                    if (s == 0) {
                        #pragma unroll
                        for (int i = 0; i < 8; ++i) {
                            skacc[lr*8+i] = kv[i];
                            sinp[lr*64+i] = sstate[lr*64+i] + 0.005f * kv[i];
                        }
                    } else if (s == 1) {
                        #pragma unroll
                        for (int i = 0; i < 8; ++i) {
                            skacc[lr*8+i] += 2.f * kv[i];
                            sinp[lr*64+i] = sstate[lr*64+i] + 0.005f * kv[i];
                        }
                    } else if (s == 2) {
                        #pragma unroll
                        for (int i = 0; i < 8; ++i) {
                            skacc[lr*8+i] += 2.f * kv[i];
                            sinp[lr*64+i] = sstate[lr*64+i] + 0.01f * kv[i];
                        }
                    } else {
                        #pragma unroll
                        for (int i = 0; i < 8; ++i) {
                            sstate[lr*64+i] += (0.01f/6.f) * (skacc[lr*8+i] + kv[i]);
                        }
                    }
                }
                if (s == 0) {
                    // z_half: yp_interp into inp[8:48)
                    int r = -1, i = 0;
                    if (j >= 8 && j < 48)        { r = r0; i = j - 8; }
                    else if (j >= 72 && j < 112) { r = r1; i = j - 72; }
                    if (r >= 0) {
                        float a  = sstate[r*64 + 8 + i];
                        float bb = (i < 32) ? sstate[r*64 + 16 + i]
                                            : sstate[r*64 + (i & 7)];
                        sinp[r*64 + 8 + i] = 0.5f * (a + bb);
                    }
                } else if (s == 2) {
                    // z_full: yp_shift into inp[8:48)
                    int r = -1, i = 0;
                    if (j >= 8 && j < 48)        { r = r0; i = j - 8; }
                    else if (j >= 72 && j < 112) { r = r1; i = j - 72; }
                    if (r >= 0) {
                        float v = (i < 32) ? sstate[r*64 + 16 + i]
                                           : sstate[r*64 + (i & 7)];
                        sinp[r*64 + 8 + i] = v;
                    }
                } else if (s == 3) {
                    // commit z+ = [yp_shift, upseq[2:], u] from inp
                    int r = -1, zi = 0;
                    if (j >= 8 && j < 58)        { r = r0; zi = j - 8; }
                    else if (j >= 72 && j < 122) { r = r1; zi = j - 72; }
                    if (r >= 0) {
                        float v = (zi < 40) ? sinp[r*64 + 8 + zi]
                                            : sinp[r*64 + 10 + zi];
                        sstate[r*64 + 8 + zi] = v;
                    }
                }
            }
            __syncthreads();
        }
    }
}

extern "C" void kernel_launch(void* const* d_in, const int* in_sizes, int n_in,
                              void* d_out, int out_size, void* d_ws, size_t ws_size,
                              hipStream_t stream) {
    const float* useq = (const float*)d_in[0];
    const float* xGz0 = (const float*)d_in[1];
    const float* W1   = (const float*)d_in[2];
    const float* b1   = (const float*)d_in[3];
    const float* W2   = (const float*)d_in[4];
    const float* b2   = (const float*)d_in[5];
    const float* W3   = (const float*)d_in[6];
    const float* b3   = (const float*)d_in[7];
    float* out = (float*)d_out;

    size_t lds = (size_t)LDS_FLOATS * sizeof(float);
    (void)hipFuncSetAttribute((const void*)cstr_rk4,
                              hipFuncAttributeMaxDynamicSharedMemorySize, (int)lds);
    hipLaunchKernelGGL(cstr_rk4, dim3(2048 / ROWS), dim3(BLOCK), lds, stream,
                       useq, xGz0, W1, b1, W2, b2, W3, b3, out);
}

// Round 2
// 2639.233 us; speedup vs baseline: 1.3363x; 1.3363x over previous
//
#include <hip/hip_runtime.h>
#include <math.h>

#define BLOCK 256
#define ROWS 4

// ---- LDS layout (dword offsets) ----
static constexpr int O_W1  = 0;       // 15 q * 256 = 3840 u32 (bf16-pair packed)
static constexpr int O_W2  = 3840;    // 32 q * 256 = 8192 u32
static constexpr int O_W3  = 12032;   // 8 * 132 = 1056 f32 (transposed, padded)
static constexpr int O_B1  = 13088;   // 128
static constexpr int O_B2  = 13216;   // 128
static constexpr int O_B3  = 13344;   // 8
static constexpr int O_YP  = 13352;   // 3 bufs * 4 rows * 40 = 480
static constexpr int O_UP  = 13832;   // 2 bufs * 4 rows * 12 = 96
static constexpr int O_SU  = 13928;   // 4 rows * 256 = 1024
static constexpr int O_H1  = 14952;   // 4 * 128
static constexpr int O_H2  = 15464;   // 4 * 128
static constexpr int O_NN  = 15976;   // 4 rows * 16 partials
static constexpr int O_XG  = 16040;   // 4 rows * 8 (xG mirror for z-build)
static constexpr int LDSN  = 16072;   // 64288 bytes -> 2 blocks/CU

__device__ __forceinline__ unsigned f2bf(float f) {   // fp32 -> bf16 (RNE)
  unsigned u = __float_as_uint(f);
  return (u + 0x7fffu + ((u >> 16) & 1u)) >> 16;
}
__device__ __forceinline__ float bflo(unsigned w) { return __uint_as_float(w << 16); }
__device__ __forceinline__ float bfhi(unsigned w) { return __uint_as_float(w & 0xffff0000u); }

__device__ __forceinline__ float tanh_fast(float x) {
  x = fminf(fmaxf(x, -15.f), 15.f);
  float e = __expf(2.f * x);
  return 1.f - __fdividef(2.f, e + 1.f);
}

// kv = scaled _fg(x,u) + nn   (scale factors folded per component)
__device__ __forceinline__ void fg_nn(const float* x, float u0, float u1,
                                      const float* nn, float* kv) {
  float Hr  = fmaf(x[0], 2.f, 50.f),  CAr = fmaf(x[1], 0.2f, 1.f);
  float CBr = fmaf(x[2], 0.1f, 0.5f), Tr  = fmaf(x[3], 4.f, 313.f);
  float Hb  = fmaf(x[4], 2.f, 50.f),  CAb = fmaf(x[5], 0.2f, 1.f);
  float CBb = fmaf(x[6], 0.1f, 0.5f), Tb  = fmaf(x[7], 4.f, 313.f);
  float F = u0 + 10.f, D = fmaf(u1, 0.5f, 5.f);
  float Fr = 2.5f * sqrtf(Hr), Fb = 1.5f * sqrtf(Hb);
  float rH = __fdividef(1.f, 3.f * Hr), rB = __fdividef(1.f, 3.f * Hb);
  kv[0] = (F + D - Fr) * (1.f / 6.f) + nn[0];
  kv[1] = (F * (6.f - CAr) - D * CAr) * (5.f * rH) + nn[1];
  kv[2] = (-(F + D) * CBr) * (10.f * rH) + nn[2];
  kv[3] = (F * (320.f - Tr) + D * (300.f - Tr)) * (0.25f * rH) + (5.f / 3.f) * rH + nn[3];
  kv[4] = (Fr - Fb - D) * (1.f / 6.f) + nn[4];
  kv[5] = (Fr * (CAr - CAb) + D * CAb) * (5.f * rB) + nn[5];
  kv[6] = (Fr * (CBr - CBb) + D * CBb) * (10.f * rB) + nn[6];
  kv[7] = Fr * (Tr - Tb) * (0.25f * rB) + (5.f / 3.f) * rB + nn[7];
}

#define L1Q(W, X0, X1) { unsigned wx_ = (W).x, wy_ = (W).y;                         \
  float l0_ = bflo(wx_), h0_ = bfhi(wx_), l1_ = bflo(wy_), h1_ = bfhi(wy_);         \
  aA0 = fmaf((X0).x, l0_, fmaf((X0).y, h0_, aA0));                                  \
  aB0 = fmaf((X0).z, l1_, fmaf((X0).w, h1_, aB0));                                  \
  aA1 = fmaf((X1).x, l0_, fmaf((X1).y, h0_, aA1));                                  \
  aB1 = fmaf((X1).z, l1_, fmaf((X1).w, h1_, aB1)); }

extern "C" __global__ void __launch_bounds__(BLOCK, 2)
cstr_rk4(const float* __restrict__ useq, const float* __restrict__ xGz0,
         const float* __restrict__ W1, const float* __restrict__ b1,
         const float* __restrict__ W2, const float* __restrict__ b2,
         const float* __restrict__ W3, const float* __restrict__ b3,
         float* __restrict__ out)
{
  extern __shared__ float sm[];
  unsigned* w1p = (unsigned*)(sm + O_W1);
  unsigned* w2p = (unsigned*)(sm + O_W2);
  float* w3t  = sm + O_W3;
  float* sb1  = sm + O_B1;
  float* sb2  = sm + O_B2;
  float* sb3  = sm + O_B3;
  float* ypb  = sm + O_YP;   // [3][4][40]
  float* upb  = sm + O_UP;   // [2][4][12]
  float* su   = sm + O_SU;   // [4][256]
  float* sh1  = sm + O_H1;   // [4][128]
  float* sh2  = sm + O_H2;   // [4][128]
  float* snnp = sm + O_NN;   // [4][16]
  float* sxg  = sm + O_XG;   // [4][8]

  const int tid  = threadIdx.x;
  const int base = blockIdx.x * ROWS;

  // ---- stage weights (bf16-pair packed along K), biases, inputs ----
  for (int i = tid; i < 3840; i += BLOCK) {
    int j = (i >> 1) & 127, q = i >> 8, half = i & 1;
    int p = 2 * q + half;  // pair p covers k=2p,2p+1
    w1p[i] = f2bf(W1[(2 * p) * 128 + j]) | (f2bf(W1[(2 * p + 1) * 128 + j]) << 16);
  }
  for (int i = tid; i < 8192; i += BLOCK) {
    int j = (i >> 1) & 127, q = i >> 8, half = i & 1;
    int p = 2 * q + half;
    w2p[i] = f2bf(W2[(2 * p) * 128 + j]) | (f2bf(W2[(2 * p + 1) * 128 + j]) << 16);
  }
  for (int i = tid; i < 1024; i += BLOCK) w3t[(i & 7) * 132 + (i >> 3)] = W3[i];
  if (tid < 128) { sb1[tid] = b1[tid]; sb2[tid] = b2[tid]; }
  if (tid < 8) sb3[tid] = b3[tid];
  for (int i = tid; i < ROWS * 256; i += BLOCK) su[i] = useq[(size_t)base * 256 + i];
  for (int i = tid; i < ROWS * 58; i += BLOCK) {
    int r = i / 58, c = i % 58;
    float v = xGz0[(size_t)(base + r) * 58 + c];
    if (c < 8)       sxg[r * 8 + c] = v;
    else if (c < 48) ypb[r * 40 + (c - 8)] = v;     // buf 0 = initial ypseq
    else             upb[r * 12 + (c - 48)] = v;    // buf 0 = initial upseq
  }
  __syncthreads();

  const int g    = tid >> 7;          // 0..1 (two row-pair groups)
  const int j    = tid & 127;
  const int r0   = 2 * g, r1 = r0 + 1;
  const int rowj = (j < 64) ? r0 : r1;   // row this lane serves in phase work
  const int l    = j & 63;

  // per-thread replicated state for its two rows
  float xg0[8], xg1[8], c0a[8], c1a[8], ka0[8], ka1[8];
  #pragma unroll
  for (int i = 0; i < 8; ++i) {
    xg0[i] = xGz0[(size_t)(base + r0) * 58 + i];
    xg1[i] = xGz0[(size_t)(base + r1) * 58 + i];
    c0a[i] = xg0[i]; c1a[i] = xg1[i];
  }

  int rot = 0;
  #pragma unroll 1
  for (int t = 0; t < 128; ++t) {
    const float u00 = su[r0 * 256 + 2 * t], u01 = su[r0 * 256 + 2 * t + 1];
    const float u10 = su[r1 * 256 + 2 * t], u11 = su[r1 * 256 + 2 * t + 1];
    const int ba = rot;
    const int bb = (rot + 1 > 2) ? rot - 2 : rot + 1;
    const int bc = (rot + 2 > 2) ? rot - 1 : rot + 2;
    const float* up0 = upb + (t & 1) * 48 + r0 * 12;
    const float* up1 = upb + (t & 1) * 48 + r1 * 12;

    #pragma unroll 1
    for (int s = 0; s < 4; ++s) {
      const int yb = (s == 0) ? ba : ((s == 3) ? bc : bb);
      const float* yA0 = ypb + yb * 160 + r0 * 40;
      const float* yA1 = ypb + yb * 160 + r1 * 40;

      // ---- L1: h1 = tanh([x | yp | up | u] @ W1 + b1), x/u from regs ----
      float aA0 = sb1[j], aB0 = 0.f, aA1 = aA0, aB1 = 0.f;
      {
        const unsigned* wp = w1p + (j << 1);
        {
          uint2 w = *(const uint2*)(wp + 0 * 256);
          float4 x0 = make_float4(c0a[0], c0a[1], c0a[2], c0a[3]);
          float4 x1 = make_float4(c1a[0], c1a[1], c1a[2], c1a[3]);
          L1Q(w, x0, x1);
        }
        {
          uint2 w = *(const uint2*)(wp + 1 * 256);
          float4 x0 = make_float4(c0a[4], c0a[5], c0a[6], c0a[7]);
          float4 x1 = make_float4(c1a[4], c1a[5], c1a[6], c1a[7]);
          L1Q(w, x0, x1);
        }
        #pragma unroll
        for (int q = 2; q < 12; ++q) {
          uint2 w = *(const uint2*)(wp + q * 256);
          float4 x0 = *(const float4*)(yA0 + 4 * (q - 2));
          float4 x1 = *(const float4*)(yA1 + 4 * (q - 2));
          L1Q(w, x0, x1);
        }
        #pragma unroll
        for (int q = 12; q < 14; ++q) {
          uint2 w = *(const uint2*)(wp + q * 256);
          float4 x0 = *(const float4*)(up0 + 4 * (q - 12));
          float4 x1 = *(const float4*)(up1 + 4 * (q - 12));
          L1Q(w, x0, x1);
        }
        {
          uint2 w = *(const uint2*)(wp + 14 * 256);
          float4 x0 = make_float4(up0[8], up0[9], u00, u01);
          float4 x1 = make_float4(up1[8], up1[9], u10, u11);
          L1Q(w, x0, x1);
        }
      }
      sh1[r0 * 128 + j] = tanh_fast(aA0 + aB0);
      sh1[r1 * 128 + j] = tanh_fast(aA1 + aB1);
      __syncthreads();

      // ---- L2: h2 = tanh(h1 @ W2 + b2) ----
      float dA0 = sb2[j], dB0 = 0.f, dA1 = dA0, dB1 = 0.f;
      {
        const unsigned* wp = w2p + (j << 1);
        const float* hh0 = sh1 + r0 * 128;
        const float* hh1 = sh1 + r1 * 128;
        #pragma unroll 8
        for (int q = 0; q < 32; ++q) {
          uint2 w = *(const uint2*)(wp + q * 256);
          float4 x0 = *(const float4*)(hh0 + 4 * q);
          float4 x1 = *(const float4*)(hh1 + 4 * q);
          unsigned wx_ = w.x, wy_ = w.y;
          float l0_ = bflo(wx_), h0_ = bfhi(wx_), l1_ = bflo(wy_), h1_ = bfhi(wy_);
          dA0 = fmaf(x0.x, l0_, fmaf(x0.y, h0_, dA0));
          dB0 = fmaf(x0.z, l1_, fmaf(x0.w, h1_, dB0));
          dA1 = fmaf(x1.x, l0_, fmaf(x1.y, h0_, dA1));
          dB1 = fmaf(x1.z, l1_, fmaf(x1.w, h1_, dB1));
        }
      }
      sh2[r0 * 128 + j] = tanh_fast(dA0 + dB0);
      sh2[r1 * 128 + j] = tanh_fast(dA1 + dB1);
      __syncthreads();

      // ---- L3 partials (16 lanes/row) || z-build (idle lanes) ----
      if (l < 16) {
        int o = l & 7, h = l >> 3;
        const float* hp = sh2 + rowj * 128 + h * 64;
        const float* wp = w3t + o * 132 + h * 64;
        float e0 = 0.f, e1 = 0.f;
        #pragma unroll
        for (int qq = 0; qq < 16; ++qq) {
          float4 hv = *(const float4*)(hp + 4 * qq);
          float4 wv = *(const float4*)(wp + 4 * qq);
          float tv = fmaf(hv.x, wv.x, fmaf(hv.y, wv.y, fmaf(hv.z, wv.z, hv.w * wv.w)));
          if (qq & 1) e1 += tv; else e0 += tv;
        }
        snnp[rowj * 16 + h * 8 + o] = e0 + e1;
      } else if (l < 56) {
        if (s == 0 || s == 2) {            // build yp_interp (s0) / yp_shift (s2)
          int i = l - 16;
          const float* ya = ypb + ba * 160 + rowj * 40;
          float bv = (i < 32) ? ya[i + 8] : sxg[rowj * 8 + (i - 32)];
          if (s == 0) (ypb + bb * 160 + rowj * 40)[i] = 0.5f * (ya[i] + bv);
          else        (ypb + bc * 160 + rowj * 40)[i] = bv;
        }
      } else {
        if (s == 0) {                      // up shift for next step + y output
          int i = l - 56;
          const float* uc = (j < 64) ? up0 : up1;
          float* un = upb + (1 - (t & 1)) * 48 + rowj * 12;
          un[i] = uc[i + 2];
          if (i < 2) un[8 + i] = (i == 0) ? ((j < 64) ? u00 : u10)
                                          : ((j < 64) ? u01 : u11);
          if (i == 7) {
            float* op = out + ((size_t)(base + rowj) * 128 + t) * 8;
            if (j < 64) {
              *(float4*)op       = make_float4(xg0[0], xg0[1], xg0[2], xg0[3]);
              *(float4*)(op + 4) = make_float4(xg0[4], xg0[5], xg0[6], xg0[7]);
            } else {
              *(float4*)op       = make_float4(xg1[0], xg1[1], xg1[2], xg1[3]);
              *(float4*)(op + 4) = make_float4(xg1[4], xg1[5], xg1[6], xg1[7]);
            }
          }
        }
      }
      __syncthreads();

      // ---- finish: kv = fg + nn, RK update (all threads, registers) ----
      float nn0[8], nn1[8], kv0[8], kv1[8];
      {
        float4 pa = *(const float4*)(snnp + r0 * 16);
        float4 pb = *(const float4*)(snnp + r0 * 16 + 4);
        float4 pc = *(const float4*)(snnp + r0 * 16 + 8);
        float4 pd = *(const float4*)(snnp + r0 * 16 + 12);
        float4 qa = *(const float4*)(snnp + r1 * 16);
        float4 qb = *(const float4*)(snnp + r1 * 16 + 4);
        float4 qc = *(const float4*)(snnp + r1 * 16 + 8);
        float4 qd = *(const float4*)(snnp + r1 * 16 + 12);
        float4 b3a = *(const float4*)(sb3);
        float4 b3b = *(const float4*)(sb3 + 4);
        nn0[0] = b3a.x + pa.x + pc.x; nn0[1] = b3a.y + pa.y + pc.y;
        nn0[2] = b3a.z + pa.z + pc.z; nn0[3] = b3a.w + pa.w + pc.w;
        nn0[4] = b3b.x + pb.x + pd.x; nn0[5] = b3b.y + pb.y + pd.y;
        nn0[6] = b3b.z + pb.z + pd.z; nn0[7] = b3b.w + pb.w + pd.w;
        nn1[0] = b3a.x + qa.x + qc.x; nn1[1] = b3a.y + qa.y + qc.y;
        nn1[2] = b3a.z + qa.z + qc.z; nn1[3] = b3a.w + qa.w + qc.w;
        nn1[4] = b3b.x + qb.x + qd.x; nn1[5] = b3b.y + qb.y + qd.y;
        nn1[6] = b3b.z + qb.z + qd.z; nn1[7] = b3b.w + qb.w + qd.w;
      }
      fg_nn(c0a, u00, u01, nn0, kv0);
      fg_nn(c1a, u10, u11, nn1, kv1);
      if (s == 0) {
        #pragma unroll
        for (int i = 0; i < 8; ++i) {
          ka0[i] = kv0[i];               ka1[i] = kv1[i];
          c0a[i] = fmaf(kv0[i], 0.005f, xg0[i]);
          c1a[i] = fmaf(kv1[i], 0.005f, xg1[i]);
        }
      } else if (s == 1) {
        #pragma unroll
        for (int i = 0; i < 8; ++i) {
          ka0[i] = fmaf(kv0[i], 2.f, ka0[i]);
          ka1[i] = fmaf(kv1[i], 2.f, ka1[i]);
          c0a[i] = fmaf(kv0[i], 0.005f, xg0[i]);
          c1a[i] = fmaf(kv1[i], 0.005f, xg1[i]);
        }
      } else if (s == 2) {
        #pragma unroll
        for (int i = 0; i < 8; ++i) {
          ka0[i] = fmaf(kv0[i], 2.f, ka0[i]);
          ka1[i] = fmaf(kv1[i], 2.f, ka1[i]);
          c0a[i] = fmaf(kv0[i], 0.01f, xg0[i]);
          c1a[i] = fmaf(kv1[i], 0.01f, xg1[i]);
        }
      } else {
        #pragma unroll
        for (int i = 0; i < 8; ++i) {
          xg0[i] = fmaf(ka0[i] + kv0[i], 0.01f / 6.f, xg0[i]);
          xg1[i] = fmaf(ka1[i] + kv1[i], 0.01f / 6.f, xg1[i]);
          c0a[i] = xg0[i]; c1a[i] = xg1[i];
        }
        if (j == 0) {   // refresh LDS xG mirror for next step's z-build
          *(float4*)(sxg + r0 * 8)     = make_float4(xg0[0], xg0[1], xg0[2], xg0[3]);
          *(float4*)(sxg + r0 * 8 + 4) = make_float4(xg0[4], xg0[5], xg0[6], xg0[7]);
          *(float4*)(sxg + r1 * 8)     = make_float4(xg1[0], xg1[1], xg1[2], xg1[3]);
          *(float4*)(sxg + r1 * 8 + 4) = make_float4(xg1[4], xg1[5], xg1[6], xg1[7]);
        }
      }
    } // s
    rot = bc;
  } // t
}

extern "C" void kernel_launch(void* const* d_in, const int* in_sizes, int n_in,
                              void* d_out, int out_size, void* d_ws, size_t ws_size,
                              hipStream_t stream) {
  const float* useq = (const float*)d_in[0];
  const float* xGz0 = (const float*)d_in[1];
  const float* W1   = (const float*)d_in[2];
  const float* b1   = (const float*)d_in[3];
  const float* W2   = (const float*)d_in[4];
  const float* b2   = (const float*)d_in[5];
  const float* W3   = (const float*)d_in[6];
  const float* b3   = (const float*)d_in[7];
  float* out = (float*)d_out;

  size_t lds = (size_t)LDSN * sizeof(float);
  (void)hipFuncSetAttribute((const void*)cstr_rk4,
                            hipFuncAttributeMaxDynamicSharedMemorySize, (int)lds);
  hipLaunchKernelGGL(cstr_rk4, dim3(2048 / ROWS), dim3(BLOCK), lds, stream,
                     useq, xGz0, W1, b1, W2, b2, W3, b3, out);
}

// Round 3
// 2345.456 us; speedup vs baseline: 1.5036x; 1.1253x over previous
//
#include <hip/hip_runtime.h>
#include <math.h>

#define BLOCK 64
#define ROWS 4

typedef __attribute__((ext_vector_type(8))) short s16x8;
typedef __attribute__((ext_vector_type(4))) float f32x4;

// ---- LDS layout (dword offsets) ----
static constexpr int O_W1  = 0;      // bf16 [128][72]  -> 4608 dw
static constexpr int O_W2  = 4608;   // bf16 [128][136] -> 8704 dw
static constexpr int O_W3  = 13312;  // bf16 [16][136]  -> 1088 dw
static constexpr int O_INB = 14400;  // bf16 [16][72]   -> 576 dw
static constexpr int O_H1  = 14976;  // bf16 [16][136]  -> 1088 dw
static constexpr int O_H2  = 16064;  // bf16 [16][136]  -> 1088 dw
static constexpr int O_B1  = 17152;  // f32 [128]
static constexpr int O_B2  = 17280;  // f32 [128]
static constexpr int O_B3  = 17408;  // f32 [8]
static constexpr int O_SU  = 17416;  // f32 [4][256]
static constexpr int O_YPM = 18440;  // f32 [4][40]
static constexpr int O_UPM = 18600;  // f32 [4][12]
static constexpr int O_XM  = 18648;  // f32 [4][8]   (stage-state mirror)
static constexpr int O_NNM = 18680;  // f32 [4][8]
static constexpr int LDSN  = 18712;  // 74848 bytes -> 2 blocks/CU

__device__ __forceinline__ unsigned short f2bf(float f) {  // fp32->bf16 RNE
  unsigned u = __float_as_uint(f);
  return (unsigned short)((u + 0x7fffu + ((u >> 16) & 1u)) >> 16);
}
__device__ __forceinline__ unsigned cvt_pk_bf16(float lo, float hi) {
  unsigned r;
  asm("v_cvt_pk_bf16_f32 %0, %1, %2" : "=v"(r) : "v"(lo), "v"(hi));
  return r;
}
__device__ __forceinline__ float tanh_fast(float x) {
  x = fminf(fmaxf(x, -15.f), 15.f);
  float e = __expf(2.f * x);
  return 1.f - __fdividef(2.f, e + 1.f);
}

extern "C" __global__ void __launch_bounds__(BLOCK)
cstr_rk4_mfma(const float* __restrict__ useq, const float* __restrict__ xGz0,
              const float* __restrict__ W1, const float* __restrict__ b1,
              const float* __restrict__ W2, const float* __restrict__ b2,
              const float* __restrict__ W3, const float* __restrict__ b3,
              float* __restrict__ out)
{
  extern __shared__ float smf[];
  unsigned* smu = (unsigned*)smf;
  unsigned short* smh = (unsigned short*)smf;

  unsigned short* w1h = smh + 2 * O_W1;   // [128][72]
  unsigned short* w2h = smh + 2 * O_W2;   // [128][136]
  unsigned short* w3h = smh + 2 * O_W3;   // [16][136]
  unsigned short* inh = smh + 2 * O_INB;  // [16][72]
  unsigned short* h1h = smh + 2 * O_H1;   // [16][136]
  unsigned short* h2h = smh + 2 * O_H2;   // [16][136]
  unsigned* h1u = smu + O_H1;
  unsigned* h2u = smu + O_H2;
  unsigned* inu = smu + O_INB;
  float* b1s = smf + O_B1;
  float* b2s = smf + O_B2;
  float* b3s = smf + O_B3;
  float* su  = smf + O_SU;   // [4][256]
  float* ypm = smf + O_YPM;  // [4][40]
  float* upm = smf + O_UPM;  // [4][12]
  float* xm  = smf + O_XM;   // [4][8]
  float* nnm = smf + O_NNM;  // [4][8]

  const int l = threadIdx.x;
  const int base = blockIdx.x * ROWS;
  const int nn = l & 15;      // frag row/col index
  const int hh = l >> 4;      // k-half group (0..3)

  // ================= staging (one-time) =================
  for (int j = 0; j < 128; ++j)
    for (int k = l; k < 72; k += 64)
      w1h[j * 72 + k] = (k < 60) ? f2bf(W1[k * 128 + j]) : (unsigned short)0;
  for (int j = 0; j < 128; ++j)
    for (int k = l; k < 136; k += 64)
      w2h[j * 136 + k] = (k < 128) ? f2bf(W2[k * 128 + j]) : (unsigned short)0;
  for (int o = 0; o < 16; ++o)
    for (int k = l; k < 136; k += 64)
      w3h[o * 136 + k] = (o < 8 && k < 128) ? f2bf(W3[k * 8 + o]) : (unsigned short)0;
  if (l < 64) { b1s[l] = b1[l]; b1s[l + 64] = b1[l + 64];
                b2s[l] = b2[l]; b2s[l + 64] = b2[l + 64]; }
  if (l < 8) b3s[l] = b3[l];
  for (int i = l; i < ROWS * 256; i += 64) su[i] = useq[(size_t)base * 256 + i];
  for (int i = l; i < 160; i += 64) {
    int r_ = i / 40, ci = i % 40;
    ypm[i] = xGz0[(size_t)(base + r_) * 58 + 8 + ci];
  }
  if (l < 48) {
    int r_ = l / 12, ci = l % 12;
    upm[l] = (ci < 10) ? xGz0[(size_t)(base + r_) * 58 + 48 + ci] : 0.f;
  }
  for (int i = l; i < 1088; i += 64) { h1u[i] = 0u; h2u[i] = 0u; }
  for (int i = l; i < 16 * 72; i += 64) {
    int n_ = i / 72, k = i % 72;
    unsigned short v = 0;
    if (n_ < ROWS && k < 60) {
      float f = (k < 58) ? xGz0[(size_t)(base + n_) * 58 + k]
                         : useq[(size_t)(base + n_) * 256 + (k - 58)];
      v = f2bf(f);
    }
    inh[i] = v;
  }
  const int r = l >> 3, c = l & 7;
  float xg = 0.f, kacc = 0.f, b3r = 0.f;
  if (l < 32) {
    xg = xGz0[(size_t)(base + r) * 58 + c];
    xm[l] = xg;
  }
  __syncthreads();
  if (l < 32) b3r = b3s[c];

  const unsigned short* inrow = inh + nn * 72;
  const unsigned short* h1row = h1h + nn * 136;
  const unsigned short* h2row = h2h + nn * 136;

  float u0r = 0.f, u1r = 0.f;

  // ================= main loop =================
  #pragma unroll 1
  for (int t = 0; t < 128; ++t) {
    if (l < 32) {
      u0r = su[r * 256 + 2 * t];
      u1r = su[r * 256 + 2 * t + 1];
      out[((size_t)(base + r) * 128 + t) * 8 + c] = xg;   // y = xG (step base)
    }

    #pragma unroll
    for (int s = 0; s < 4; ++s) {
      // ---------- L1: C1 = W1^T @ inb^T ----------
      f32x4 c1[8];
      #pragma unroll
      for (int m = 0; m < 8; ++m) c1[m] = (f32x4){0.f, 0.f, 0.f, 0.f};
      {
        s16x8 bb0 = *(const s16x8*)(inrow + 8 * hh);
        s16x8 bb1 = *(const s16x8*)(inrow + 32 + 8 * hh);
        #pragma unroll
        for (int m = 0; m < 8; ++m) {
          const unsigned short* w = w1h + (16 * m + nn) * 72 + 8 * hh;
          s16x8 a0 = *(const s16x8*)(w);
          s16x8 a1 = *(const s16x8*)(w + 32);
          c1[m] = __builtin_amdgcn_mfma_f32_16x16x32_bf16(a0, bb0, c1[m], 0, 0, 0);
          c1[m] = __builtin_amdgcn_mfma_f32_16x16x32_bf16(a1, bb1, c1[m], 0, 0, 0);
        }
      }
      if (nn < ROWS) {   // valid cols = batch rows
        #pragma unroll
        for (int m = 0; m < 8; ++m) {
          float4 bv = *(const float4*)(b1s + 16 * m + 4 * hh);
          float t0 = tanh_fast(c1[m][0] + bv.x);
          float t1 = tanh_fast(c1[m][1] + bv.y);
          float t2 = tanh_fast(c1[m][2] + bv.z);
          float t3 = tanh_fast(c1[m][3] + bv.w);
          uint2 pk; pk.x = cvt_pk_bf16(t0, t1); pk.y = cvt_pk_bf16(t2, t3);
          *(uint2*)(h1u + nn * 68 + 8 * m + 2 * hh) = pk;
        }
      }

      // ---------- L2: C2 = W2^T @ h1^T ----------
      f32x4 c2[8];
      #pragma unroll
      for (int m = 0; m < 8; ++m) c2[m] = (f32x4){0.f, 0.f, 0.f, 0.f};
      {
        s16x8 bb[4];
        #pragma unroll
        for (int p = 0; p < 4; ++p)
          bb[p] = *(const s16x8*)(h1row + 32 * p + 8 * hh);
        #pragma unroll
        for (int m = 0; m < 8; ++m) {
          const unsigned short* w = w2h + (16 * m + nn) * 136 + 8 * hh;
          #pragma unroll
          for (int p = 0; p < 4; ++p) {
            s16x8 a = *(const s16x8*)(w + 32 * p);
            c2[m] = __builtin_amdgcn_mfma_f32_16x16x32_bf16(a, bb[p], c2[m], 0, 0, 0);
          }
        }
      }
      if (nn < ROWS) {
        #pragma unroll
        for (int m = 0; m < 8; ++m) {
          float4 bv = *(const float4*)(b2s + 16 * m + 4 * hh);
          float t0 = tanh_fast(c2[m][0] + bv.x);
          float t1 = tanh_fast(c2[m][1] + bv.y);
          float t2 = tanh_fast(c2[m][2] + bv.z);
          float t3 = tanh_fast(c2[m][3] + bv.w);
          uint2 pk; pk.x = cvt_pk_bf16(t0, t1); pk.y = cvt_pk_bf16(t2, t3);
          *(uint2*)(h2u + nn * 68 + 8 * m + 2 * hh) = pk;
        }
      }

      // ---------- L3: C3 = W3^T @ h2^T ----------
      {
        f32x4 c3 = (f32x4){0.f, 0.f, 0.f, 0.f};
        #pragma unroll
        for (int p = 0; p < 4; ++p) {
          s16x8 a = *(const s16x8*)(w3h + nn * 136 + 32 * p + 8 * hh);
          s16x8 b = *(const s16x8*)(h2row + 32 * p + 8 * hh);
          c3 = __builtin_amdgcn_mfma_f32_16x16x32_bf16(a, b, c3, 0, 0, 0);
        }
        if (nn < ROWS && hh < 2) {   // rows(comps) 4*hh+r valid, col nn = batch row
          nnm[nn * 8 + 4 * hh + 0] = c3[0];
          nnm[nn * 8 + 4 * hh + 1] = c3[1];
          nnm[nn * 8 + 4 * hh + 2] = c3[2];
          nnm[nn * 8 + 4 * hh + 3] = c3[3];
        }
      }

      // ---------- state: kv = fg + nn; RK; z maintenance ----------
      if (l < 32) {
        float nv = nnm[r * 8 + c] + b3r;
        float4 xa = *(const float4*)(xm + r * 8);
        float4 xb = *(const float4*)(xm + r * 8 + 4);
        float Hr  = fmaf(xa.x, 2.f, 50.f),  CAr = fmaf(xa.y, 0.2f, 1.f);
        float CBr = fmaf(xa.z, 0.1f, 0.5f), Tr  = fmaf(xa.w, 4.f, 313.f);
        float Hb  = fmaf(xb.x, 2.f, 50.f),  CAb = fmaf(xb.y, 0.2f, 1.f);
        float CBb = fmaf(xb.z, 0.1f, 0.5f), Tb  = fmaf(xb.w, 4.f, 313.f);
        float F = u0r + 10.f, D = fmaf(u1r, 0.5f, 5.f);
        float Fr = 2.5f * sqrtf(Hr), Fb = 1.5f * sqrtf(Hb);
        float rH = __fdividef(1.f, 3.f * Hr), rB = __fdividef(1.f, 3.f * Hb);
        float k0 = (F + D - Fr) * (1.f / 6.f);
        float k1 = (F * (6.f - CAr) - D * CAr) * (5.f * rH);
        float k2 = (-(F + D) * CBr) * (10.f * rH);
        float k3 = (F * (320.f - Tr) + D * (300.f - Tr)) * (0.25f * rH) + (5.f / 3.f) * rH;
        float k4 = (Fr - Fb - D) * (1.f / 6.f);
        float k5 = (Fr * (CAr - CAb) + D * CAb) * (5.f * rB);
        float k6 = (Fr * (CBr - CBb) + D * CBb) * (10.f * rB);
        float k7 = Fr * (Tr - Tb) * (0.25f * rB) + (5.f / 3.f) * rB;
        float fgc = (c & 4) ? ((c & 2) ? ((c & 1) ? k7 : k6) : ((c & 1) ? k5 : k4))
                            : ((c & 2) ? ((c & 1) ? k3 : k2) : ((c & 1) ? k1 : k0));
        float kv = fgc + nv;
        float cc;
        if (s == 0)      { kacc = kv;                 cc = fmaf(kv, 0.005f, xg); }
        else if (s == 1) { kacc = fmaf(kv, 2.f, kacc); cc = fmaf(kv, 0.005f, xg); }
        else if (s == 2) { kacc = fmaf(kv, 2.f, kacc); cc = fmaf(kv, 0.01f,  xg); }
        else             { xg = fmaf(kacc + kv, 0.01f / 6.f, xg); cc = xg; }
        inh[r * 72 + c] = f2bf(cc);
        xm[r * 8 + c] = cc;

        if (s == 0) {            // yp_interp for k2/k3
          float a0 = ypm[r * 40 + c],      a1 = ypm[r * 40 + 8 + c];
          float a2 = ypm[r * 40 + 16 + c], a3 = ypm[r * 40 + 24 + c];
          float a4 = ypm[r * 40 + 32 + c], a5 = xg;
          inh[r * 72 + 8 + c]  = f2bf(0.5f * (a0 + a1));
          inh[r * 72 + 16 + c] = f2bf(0.5f * (a1 + a2));
          inh[r * 72 + 24 + c] = f2bf(0.5f * (a2 + a3));
          inh[r * 72 + 32 + c] = f2bf(0.5f * (a3 + a4));
          inh[r * 72 + 40 + c] = f2bf(0.5f * (a4 + a5));
        } else if (s == 2) {     // yp_shift for k4 (and next step's ypseq)
          float a1 = ypm[r * 40 + 8 + c],  a2 = ypm[r * 40 + 16 + c];
          float a3 = ypm[r * 40 + 24 + c], a4 = ypm[r * 40 + 32 + c];
          float a5 = xg;
          inh[r * 72 + 8 + c]  = f2bf(a1);
          inh[r * 72 + 16 + c] = f2bf(a2);
          inh[r * 72 + 24 + c] = f2bf(a3);
          inh[r * 72 + 32 + c] = f2bf(a4);
          inh[r * 72 + 40 + c] = f2bf(a5);
          ypm[r * 40 + c]      = a1;
          ypm[r * 40 + 8 + c]  = a2;
          ypm[r * 40 + 16 + c] = a3;
          ypm[r * 40 + 24 + c] = a4;
          ypm[r * 40 + 32 + c] = a5;
        } else if (s == 3) {     // upseq shift + next-step u
          float nu = upm[r * 12 + c + 2];   // all lanes read before any write
          upm[r * 12 + c] = nu;
          inh[r * 72 + 48 + c] = f2bf(nu);
          if (c < 2) {
            float uv = (c == 0) ? u0r : u1r;
            upm[r * 12 + 8 + c] = uv;
            inh[r * 72 + 56 + c] = f2bf(uv);
            if (t < 127)
              inh[r * 72 + 58 + c] = f2bf(su[r * 256 + 2 * (t + 1) + c]);
          }
        }
      }
    } // s
  } // t
}

extern "C" void kernel_launch(void* const* d_in, const int* in_sizes, int n_in,
                              void* d_out, int out_size, void* d_ws, size_t ws_size,
                              hipStream_t stream) {
  const float* useq = (const float*)d_in[0];
  const float* xGz0 = (const float*)d_in[1];
  const float* W1   = (const float*)d_in[2];
  const float* b1   = (const float*)d_in[3];
  const float* W2   = (const float*)d_in[4];
  const float* b2   = (const float*)d_in[5];
  const float* W3   = (const float*)d_in[6];
  const float* b3   = (const float*)d_in[7];
  float* out = (float*)d_out;

  size_t lds = (size_t)LDSN * sizeof(float);
  (void)hipFuncSetAttribute((const void*)cstr_rk4_mfma,
                            hipFuncAttributeMaxDynamicSharedMemorySize, (int)lds);
  hipLaunchKernelGGL(cstr_rk4_mfma, dim3(2048 / ROWS), dim3(BLOCK), lds, stream,
                     useq, xGz0, W1, b1, W2, b2, W3, b3, out);
}

// Round 4
// 593.324 us; speedup vs baseline: 5.9440x; 3.9531x over previous
//
#include <hip/hip_runtime.h>
#include <math.h>

#define BLOCK 256
#define ROWS 16

typedef __attribute__((ext_vector_type(8))) short s16x8;
typedef __attribute__((ext_vector_type(4))) float f32x4;

// ---- LDS layout (dword offsets), all 16B-aligned where b128-read ----
static constexpr int O_W1  = 0;      // bf16 [128][72]  -> 4608 dw
static constexpr int O_W2  = 4608;   // bf16 [128][136] -> 8704 dw
static constexpr int O_W3  = 13312;  // bf16 [16][136]  -> 1088 dw
static constexpr int O_INB = 14400;  // bf16 [16][72]   -> 576 dw
static constexpr int O_H1  = 14976;  // bf16 [16][136]  -> 1088 dw
static constexpr int O_H2  = 16064;  // bf16 [16][136]  -> 1088 dw
static constexpr int O_B1  = 17152;  // f32 [128]
static constexpr int O_B2  = 17280;  // f32 [128]
static constexpr int O_B3  = 17408;  // f32 [8]
static constexpr int O_SU  = 17416;  // f32 [16][256] = 4096 dw
static constexpr int O_YPM = 21512;  // f32 [16][40]  = 640 dw
static constexpr int O_UPM = 22152;  // f32 [16][12]  = 192 dw
static constexpr int O_XM  = 22344;  // f32 [16][8]   = 128 dw
static constexpr int O_NNP = 22472;  // f32 [4][16][8] = 512 dw (L3 partials)
static constexpr int LDSN  = 22984;  // 91936 bytes

__device__ __forceinline__ unsigned short f2bf(float f) {  // fp32->bf16 RNE
  unsigned u = __float_as_uint(f);
  return (unsigned short)((u + 0x7fffu + ((u >> 16) & 1u)) >> 16);
}
__device__ __forceinline__ unsigned cvt_pk_bf16(float lo, float hi) {
  unsigned r;
  asm("v_cvt_pk_bf16_f32 %0, %1, %2" : "=v"(r) : "v"(lo), "v"(hi));
  return r;
}
// tanh(x) = 1 - 2/(exp2(2*log2e*x)+1); saturates correctly at +/-inf, no clamp
__device__ __forceinline__ float tanh_fast(float x) {
  float e = __builtin_amdgcn_exp2f(x * 2.88539008177792681f);
  return fmaf(-2.f, __builtin_amdgcn_rcpf(e + 1.f), 1.f);
}

#define MFMA16(A, B, C) __builtin_amdgcn_mfma_f32_16x16x32_bf16((A), (B), (C), 0, 0, 0)

#define PACK_OUT(C, BV, DST) {                        \
  float t0_ = tanh_fast((C)[0] + (BV).x);             \
  float t1_ = tanh_fast((C)[1] + (BV).y);             \
  float t2_ = tanh_fast((C)[2] + (BV).z);             \
  float t3_ = tanh_fast((C)[3] + (BV).w);             \
  uint2 pk_; pk_.x = cvt_pk_bf16(t0_, t1_);           \
  pk_.y = cvt_pk_bf16(t2_, t3_);                      \
  *(uint2*)(DST) = pk_; }

extern "C" __global__ void __launch_bounds__(BLOCK, 1)
cstr_rk4_mfma4(const float* __restrict__ useq, const float* __restrict__ xGz0,
               const float* __restrict__ W1, const float* __restrict__ b1,
               const float* __restrict__ W2, const float* __restrict__ b2,
               const float* __restrict__ W3, const float* __restrict__ b3,
               float* __restrict__ out)
{
  extern __shared__ float smf[];
  unsigned* smu = (unsigned*)smf;
  unsigned short* smh = (unsigned short*)smf;

  unsigned short* w1h = smh + 2 * O_W1;   // [128][72]
  unsigned short* w2h = smh + 2 * O_W2;   // [128][136]
  unsigned short* w3h = smh + 2 * O_W3;   // [16][136]
  unsigned short* inh = smh + 2 * O_INB;  // [16][72]
  unsigned short* h1h = smh + 2 * O_H1;   // [16][136]
  unsigned short* h2h = smh + 2 * O_H2;
  unsigned* h1u = smu + O_H1;
  unsigned* h2u = smu + O_H2;
  float* b1s = smf + O_B1;
  float* b2s = smf + O_B2;
  float* b3s = smf + O_B3;
  float* su  = smf + O_SU;    // [16][256]
  float* ypm = smf + O_YPM;   // [16][40]
  float* upm = smf + O_UPM;   // [16][12]
  float* xm  = smf + O_XM;    // [16][8]
  float* nnp = smf + O_NNP;   // [4][16][8]

  const int tid  = threadIdx.x;
  const int w    = tid >> 6;     // wave 0..3
  const int l    = tid & 63;
  const int nn   = l & 15;       // frag col (batch row)
  const int hh   = l >> 4;       // k-quarter
  const int base = blockIdx.x * ROWS;

  // ================= one-time staging =================
  for (int i = tid; i < 128 * 72; i += BLOCK) {
    int j = i / 72, k = i % 72;
    w1h[i] = (k < 60) ? f2bf(W1[k * 128 + j]) : (unsigned short)0;
  }
  for (int i = tid; i < 128 * 136; i += BLOCK) {
    int j = i / 136, k = i % 136;
    w2h[i] = (k < 128) ? f2bf(W2[k * 128 + j]) : (unsigned short)0;
  }
  for (int i = tid; i < 16 * 136; i += BLOCK) {
    int o = i / 136, k = i % 136;
    w3h[i] = (o < 8 && k < 128) ? f2bf(W3[k * 8 + o]) : (unsigned short)0;
  }
  if (tid < 128) { b1s[tid] = b1[tid]; b2s[tid] = b2[tid]; }
  if (tid < 8) b3s[tid] = b3[tid];
  for (int i = tid; i < ROWS * 256; i += BLOCK) su[i] = useq[(size_t)base * 256 + i];
  for (int i = tid; i < ROWS * 40; i += BLOCK) {
    int r_ = i / 40, ci = i % 40;
    ypm[i] = xGz0[(size_t)(base + r_) * 58 + 8 + ci];
  }
  for (int i = tid; i < ROWS * 12; i += BLOCK) {
    int r_ = i / 12, ci = i % 12;
    upm[i] = (ci < 10) ? xGz0[(size_t)(base + r_) * 58 + 48 + ci] : 0.f;
  }
  for (int i = tid; i < ROWS * 8; i += BLOCK)
    xm[i] = xGz0[(size_t)(base + (i >> 3)) * 58 + (i & 7)];
  for (int i = tid; i < 16 * 72; i += BLOCK) {
    int n_ = i / 72, k = i % 72;
    unsigned short v = 0;
    if (k < 58)      v = f2bf(xGz0[(size_t)(base + n_) * 58 + k]);
    else if (k < 60) v = f2bf(useq[(size_t)(base + n_) * 256 + (k - 58)]);
    inh[i] = v;
  }

  // state lanes: wave w owns rows 4w..4w+3; lane l<32 -> (row, comp)
  const int sr = 4 * w + ((l >> 3) & 3);
  const int sc = l & 7;
  const bool st = (l < 32);
  float xg = 0.f, kacc = 0.f, b3r = 0.f;
  if (st) xg = xGz0[(size_t)(base + sr) * 58 + sc];

  __syncthreads();
  if (st) b3r = b3s[sc];

  // ====== loop-invariant weight fragments + biases -> registers ======
  const int mb0 = 2 * w, mb1 = 2 * w + 1;
  const s16x8 a10 = *(const s16x8*)(w1h + (16 * mb0 + nn) * 72 + 8 * hh);
  const s16x8 a11 = *(const s16x8*)(w1h + (16 * mb0 + nn) * 72 + 32 + 8 * hh);
  const s16x8 a12 = *(const s16x8*)(w1h + (16 * mb1 + nn) * 72 + 8 * hh);
  const s16x8 a13 = *(const s16x8*)(w1h + (16 * mb1 + nn) * 72 + 32 + 8 * hh);
  const s16x8 a200 = *(const s16x8*)(w2h + (16 * mb0 + nn) * 136 +  0 + 8 * hh);
  const s16x8 a201 = *(const s16x8*)(w2h + (16 * mb0 + nn) * 136 + 32 + 8 * hh);
  const s16x8 a202 = *(const s16x8*)(w2h + (16 * mb0 + nn) * 136 + 64 + 8 * hh);
  const s16x8 a203 = *(const s16x8*)(w2h + (16 * mb0 + nn) * 136 + 96 + 8 * hh);
  const s16x8 a210 = *(const s16x8*)(w2h + (16 * mb1 + nn) * 136 +  0 + 8 * hh);
  const s16x8 a211 = *(const s16x8*)(w2h + (16 * mb1 + nn) * 136 + 32 + 8 * hh);
  const s16x8 a212 = *(const s16x8*)(w2h + (16 * mb1 + nn) * 136 + 64 + 8 * hh);
  const s16x8 a213 = *(const s16x8*)(w2h + (16 * mb1 + nn) * 136 + 96 + 8 * hh);
  const s16x8 a3r  = *(const s16x8*)(w3h + nn * 136 + 32 * w + 8 * hh);
  const float4 bva0 = *(const float4*)(b1s + 16 * mb0 + 4 * hh);
  const float4 bva1 = *(const float4*)(b1s + 16 * mb1 + 4 * hh);
  const float4 bvb0 = *(const float4*)(b2s + 16 * mb0 + 4 * hh);
  const float4 bvb1 = *(const float4*)(b2s + 16 * mb1 + 4 * hh);

  const unsigned short* inrow = inh + nn * 72;
  const unsigned short* h1row = h1h + nn * 136;

  // ================= main loop =================
  #pragma unroll 1
  for (int t = 0; t < 128; ++t) {
    float u0r = 0.f, u1r = 0.f;
    if (st) {
      u0r = su[sr * 256 + 2 * t];
      u1r = su[sr * 256 + 2 * t + 1];
      out[((size_t)(base + sr) * 128 + t) * 8 + sc] = xg;   // y_t = xG
    }

    #pragma unroll
    for (int s = 0; s < 4; ++s) {
      // ---------- L1 (this wave's 32 neurons) ----------
      {
        s16x8 bb0 = *(const s16x8*)(inrow + 8 * hh);
        s16x8 bb1 = *(const s16x8*)(inrow + 32 + 8 * hh);
        f32x4 c1a = (f32x4){0.f, 0.f, 0.f, 0.f};
        f32x4 c1b = (f32x4){0.f, 0.f, 0.f, 0.f};
        c1a = MFMA16(a10, bb0, c1a); c1a = MFMA16(a11, bb1, c1a);
        c1b = MFMA16(a12, bb0, c1b); c1b = MFMA16(a13, bb1, c1b);
        PACK_OUT(c1a, bva0, h1u + nn * 68 + 8 * mb0 + 2 * hh);
        PACK_OUT(c1b, bva1, h1u + nn * 68 + 8 * mb1 + 2 * hh);
      }
      __syncthreads();

      // ---------- L2 (this wave's 32 neurons, full K=128) ----------
      {
        s16x8 q0 = *(const s16x8*)(h1row +  0 + 8 * hh);
        s16x8 q1 = *(const s16x8*)(h1row + 32 + 8 * hh);
        s16x8 q2 = *(const s16x8*)(h1row + 64 + 8 * hh);
        s16x8 q3 = *(const s16x8*)(h1row + 96 + 8 * hh);
        f32x4 c2a = (f32x4){0.f, 0.f, 0.f, 0.f};
        f32x4 c2b = (f32x4){0.f, 0.f, 0.f, 0.f};
        c2a = MFMA16(a200, q0, c2a); c2a = MFMA16(a201, q1, c2a);
        c2a = MFMA16(a202, q2, c2a); c2a = MFMA16(a203, q3, c2a);
        c2b = MFMA16(a210, q0, c2b); c2b = MFMA16(a211, q1, c2b);
        c2b = MFMA16(a212, q2, c2b); c2b = MFMA16(a213, q3, c2b);
        PACK_OUT(c2a, bvb0, h2u + nn * 68 + 8 * mb0 + 2 * hh);
        PACK_OUT(c2b, bvb1, h2u + nn * 68 + 8 * mb1 + 2 * hh);
      }
      __syncthreads();

      // ---------- L3: K split across waves (k in [32w,32w+32)) ----------
      {
        s16x8 bf = *(const s16x8*)(h2h + nn * 136 + 32 * w + 8 * hh);
        f32x4 c3 = (f32x4){0.f, 0.f, 0.f, 0.f};
        c3 = MFMA16(a3r, bf, c3);
        if (hh < 2)   // output rows o=4hh+i valid for o<8
          *(float4*)(nnp + w * 128 + nn * 8 + 4 * hh) =
              make_float4(c3[0], c3[1], c3[2], c3[3]);
      }
      __syncthreads();

      // ---------- state: kv = fg + nn; RK; z maintenance (wave-local rows) ----------
      if (st) {
        float nv = b3r + nnp[sr * 8 + sc] + nnp[128 + sr * 8 + sc]
                       + nnp[256 + sr * 8 + sc] + nnp[384 + sr * 8 + sc];
        float4 xa = *(const float4*)(xm + sr * 8);
        float4 xb = *(const float4*)(xm + sr * 8 + 4);
        float Hr  = fmaf(xa.x, 2.f, 50.f),  CAr = fmaf(xa.y, 0.2f, 1.f);
        float CBr = fmaf(xa.z, 0.1f, 0.5f), Tr  = fmaf(xa.w, 4.f, 313.f);
        float Hb  = fmaf(xb.x, 2.f, 50.f),  CAb = fmaf(xb.y, 0.2f, 1.f);
        float CBb = fmaf(xb.z, 0.1f, 0.5f), Tb  = fmaf(xb.w, 4.f, 313.f);
        float F = u0r + 10.f, D = fmaf(u1r, 0.5f, 5.f);
        float Fr = 2.5f * sqrtf(Hr), Fb = 1.5f * sqrtf(Hb);
        float rH = __builtin_amdgcn_rcpf(3.f * Hr);
        float rB = __builtin_amdgcn_rcpf(3.f * Hb);
        float k0 = (F + D - Fr) * (1.f / 6.f);
        float k1 = (F * (6.f - CAr) - D * CAr) * (5.f * rH);
        float k2 = (-(F + D) * CBr) * (10.f * rH);
        float k3 = (F * (320.f - Tr) + D * (300.f - Tr)) * (0.25f * rH) + (5.f / 3.f) * rH;
        float k4 = (Fr - Fb - D) * (1.f / 6.f);
        float k5 = (Fr * (CAr - CAb) + D * CAb) * (5.f * rB);
        float k6 = (Fr * (CBr - CBb) + D * CBb) * (10.f * rB);
        float k7 = Fr * (Tr - Tb) * (0.25f * rB) + (5.f / 3.f) * rB;
        float fgc = (sc & 4) ? ((sc & 2) ? ((sc & 1) ? k7 : k6) : ((sc & 1) ? k5 : k4))
                             : ((sc & 2) ? ((sc & 1) ? k3 : k2) : ((sc & 1) ? k1 : k0));
        float kv = fgc + nv;
        float cc;
        if (s == 0)      { kacc = kv;                  cc = fmaf(kv, 0.005f, xg); }
        else if (s == 1) { kacc = fmaf(kv, 2.f, kacc); cc = fmaf(kv, 0.005f, xg); }
        else if (s == 2) { kacc = fmaf(kv, 2.f, kacc); cc = fmaf(kv, 0.01f,  xg); }
        else             { xg = fmaf(kacc + kv, 0.01f / 6.f, xg); cc = xg; }
        inh[sr * 72 + sc] = f2bf(cc);
        xm[sr * 8 + sc] = cc;

        if (s == 0) {            // yp_interp for k2/k3
          float a0 = ypm[sr * 40 + sc],      a1 = ypm[sr * 40 + 8 + sc];
          float a2 = ypm[sr * 40 + 16 + sc], a3 = ypm[sr * 40 + 24 + sc];
          float a4 = ypm[sr * 40 + 32 + sc], a5 = xg;
          inh[sr * 72 + 8 + sc]  = f2bf(0.5f * (a0 + a1));
          inh[sr * 72 + 16 + sc] = f2bf(0.5f * (a1 + a2));
          inh[sr * 72 + 24 + sc] = f2bf(0.5f * (a2 + a3));
          inh[sr * 72 + 32 + sc] = f2bf(0.5f * (a3 + a4));
          inh[sr * 72 + 40 + sc] = f2bf(0.5f * (a4 + a5));
        } else if (s == 2) {     // yp_shift for k4 + rotate ypm
          float a1 = ypm[sr * 40 + 8 + sc],  a2 = ypm[sr * 40 + 16 + sc];
          float a3 = ypm[sr * 40 + 24 + sc], a4 = ypm[sr * 40 + 32 + sc];
          float a5 = xg;
          inh[sr * 72 + 8 + sc]  = f2bf(a1);
          inh[sr * 72 + 16 + sc] = f2bf(a2);
          inh[sr * 72 + 24 + sc] = f2bf(a3);
          inh[sr * 72 + 32 + sc] = f2bf(a4);
          inh[sr * 72 + 40 + sc] = f2bf(a5);
          ypm[sr * 40 + sc]      = a1;
          ypm[sr * 40 + 8 + sc]  = a2;
          ypm[sr * 40 + 16 + sc] = a3;
          ypm[sr * 40 + 24 + sc] = a4;
          ypm[sr * 40 + 32 + sc] = a5;
        } else if (s == 3) {     // upseq shift + next-step u
          float nu = upm[sr * 12 + sc + 2];
          upm[sr * 12 + sc] = nu;
          inh[sr * 72 + 48 + sc] = f2bf(nu);
          if (sc < 2) {
            float uv = (sc == 0) ? u0r : u1r;
            upm[sr * 12 + 8 + sc] = uv;
            inh[sr * 72 + 56 + sc] = f2bf(uv);
            if (t < 127)
              inh[sr * 72 + 58 + sc] = f2bf(su[sr * 256 + 2 * (t + 1) + sc]);
          }
        }
      }
      __syncthreads();
    } // s
  } // t
}

extern "C" void kernel_launch(void* const* d_in, const int* in_sizes, int n_in,
                              void* d_out, int out_size, void* d_ws, size_t ws_size,
                              hipStream_t stream) {
  const float* useq = (const float*)d_in[0];
  const float* xGz0 = (const float*)d_in[1];
  const float* W1   = (const float*)d_in[2];
  const float* b1   = (const float*)d_in[3];
  const float* W2   = (const float*)d_in[4];
  const float* b2   = (const float*)d_in[5];
  const float* W3   = (const float*)d_in[6];
  const float* b3   = (const float*)d_in[7];
  float* out = (float*)d_out;

  size_t lds = (size_t)LDSN * sizeof(float);
  (void)hipFuncSetAttribute((const void*)cstr_rk4_mfma4,
                            hipFuncAttributeMaxDynamicSharedMemorySize, (int)lds);
  hipLaunchKernelGGL(cstr_rk4_mfma4, dim3(2048 / ROWS), dim3(BLOCK), lds, stream,
                     useq, xGz0, W1, b1, W2, b2, W3, b3, out);
}